// Round 2
// 198.413 us; speedup vs baseline: 1.0828x; 1.0828x over previous
//
#include <hip/hip_runtime.h>
#include <hip/hip_bf16.h>

// MHA: B=2, T=2048, DIM=1024, H=16, HD=64. fp32 in/out, bf16 internal.
// R18 = R17 with the permlane32_swap operand-role fix. attn uses 32x32x16
// MFMA + swapped QK^T (S^T: q=lane&31) so the P matrix never touches LDS:
// v_perm_b32 bf16-pack + v_permlane32_swap_b32 build the PV A-frags in
// registers (T12). semantics: swap(a,b) -> a'=[a(0:31)|b(0:31)],
// b'=[a(32:63)|b(32:63)]; frag word0 = swap(pk_lo, pk_hi).first.
// Removes 32 ds_write_b16 + 4 ds_read_b128 per wave-iter (P round-trip) and
// the 18KB Ps buffer (LDS 55296->36864). K/V staging layouts (KVS=36) = R9.
// GEMMs/conv unchanged (R11).

using bf16x8 = __attribute__((ext_vector_type(8))) short;   // 8 bf16 in 4 VGPRs
using f32x4  = __attribute__((ext_vector_type(4))) float;   // 16x16 MFMA acc
using f32x16 = __attribute__((ext_vector_type(16))) float;  // 32x32 MFMA acc
using u32x4  = __attribute__((ext_vector_type(4))) unsigned int;

static __device__ __forceinline__ unsigned short f2bf(float f) {
    unsigned int u = __float_as_uint(f);
    unsigned int r = u + 0x7fffu + ((u >> 16) & 1u);   // RNE
    return (unsigned short)(r >> 16);
}

// v_permlane32_swap_b32 a, b:  a' = [a(0:31) | b(0:31)], b' = [a(32:63) | b(32:63)]
static __device__ __forceinline__ void pl32swap(unsigned int& a, unsigned int& b) {
    asm("v_permlane32_swap_b32 %0, %1" : "+v"(a), "+v"(b));
}

// async global->LDS DMA, 16 B/lane; lds dst wave-uniform (HW adds lane*16)
#define GLDS16(g, l) __builtin_amdgcn_global_load_lds(                    \
    (const __attribute__((address_space(1))) void*)(g),                   \
    (__attribute__((address_space(3))) void*)(l), 16, 0, 0)

// ---------------------------------------------------------------------------
// Fused conversions: id<2048 -> x fp32->bf16; id>=2048 -> W fp32 -> WT bf16.
// ---------------------------------------------------------------------------
__global__ __launch_bounds__(256) void conv(
    const float* __restrict__ x,
    const float* __restrict__ Wq, const float* __restrict__ Wk,
    const float* __restrict__ Wv, const float* __restrict__ Wo,
    ushort* __restrict__ xb, ushort* __restrict__ WT)
{
    int id = blockIdx.x;
    if (id < 2048) {
        int i8 = (id * 256 + threadIdx.x) * 8;
        float4 a = *reinterpret_cast<const float4*>(x + i8);
        float4 b = *reinterpret_cast<const float4*>(x + i8 + 4);
        ushort t[8] = {f2bf(a.x), f2bf(a.y), f2bf(a.z), f2bf(a.w),
                       f2bf(b.x), f2bf(b.y), f2bf(b.z), f2bf(b.w)};
        *reinterpret_cast<uint4*>(xb + i8) = *reinterpret_cast<const uint4*>(t);
    } else {
        int wid = id - 2048;
        int z   = wid >> 9;
        const float* src = (z == 0) ? Wq : (z == 1) ? Wk : (z == 2) ? Wv : Wo;
        ushort* dst = WT + (size_t)z * 1024 * 1024;
        int idx = (wid & 511) * 256 + threadIdx.x;
        int n   = idx & 1023;
        int k8  = (idx >> 10) << 3;
        ushort t[8];
#pragma unroll
        for (int e = 0; e < 8; e++) t[e] = f2bf(src[(size_t)(k8 + e) * 1024 + n]);
        *reinterpret_cast<uint4*>(dst + (size_t)n * 1024 + k8) =
            *reinterpret_cast<const uint4*>(t);
    }
}

// ---------------------------------------------------------------------------
// Fused QKV GEMM (R11) -> q (scaled 0.125*log2e), k, vT. XCD-swizzled.
// ---------------------------------------------------------------------------
#define CS 136

__global__ __launch_bounds__(256) void gemm_qkv(
    const ushort* __restrict__ Xb, const ushort* __restrict__ WT,
    const float* __restrict__ bq, const float* __restrict__ bk,
    const float* __restrict__ bv,
    ushort* __restrict__ q, ushort* __restrict__ k, ushort* __restrict__ v)
{
    __shared__ ushort smem[128 * CS];

    const int tid  = threadIdx.x;
    const int lane = tid & 63, wave = tid >> 6;
    const int l16  = lane & 15, quad = lane >> 4;
    const int wm   = (wave >> 1) * 64, wn = (wave & 1) * 64;
    const int flat = blockIdx.y * 24 + blockIdx.x;
    const int xcd  = flat & 7, lid = flat >> 3;
    const int mI   = xcd * 4 + (lid & 3);
    const int nI   = lid >> 2;
    const int m0   = mI * 128;
    const int n0g  = nI * 128;
    const int srow = lane >> 2, skoff = (lane & 3) * 8;

    f32x4 acc[4][4] = {};

#pragma unroll
    for (int c = 0; c < 2; c++) {
        int chunk = wave + c * 4;
        int row   = chunk * 16 + srow;
        GLDS16(Xb + (size_t)(m0 + row) * 1024 + skoff, smem + chunk * 512);
        GLDS16(WT + (size_t)(n0g + row) * 1024 + skoff, smem + 8192 + chunk * 512);
    }

    for (int i = 0; i < 32; i++) {
        const int p = i & 1;
        __syncthreads();
        if (i < 31) {
            int k0 = (i + 1) * 32;
#pragma unroll
            for (int c = 0; c < 2; c++) {
                int chunk = wave + c * 4;
                int row   = chunk * 16 + srow;
                GLDS16(Xb + (size_t)(m0 + row) * 1024 + k0 + skoff,
                       smem + (p ^ 1) * 4096 + chunk * 512);
                GLDS16(WT + (size_t)(n0g + row) * 1024 + k0 + skoff,
                       smem + 8192 + (p ^ 1) * 4096 + chunk * 512);
            }
        }
        const ushort* As = smem + p * 4096;
        const ushort* Bs = smem + 8192 + p * 4096;
        bf16x8 af[4], bfr[4];
#pragma unroll
        for (int t = 0; t < 4; t++) {
            af[t]  = *(const bf16x8*)&As[(wm + t * 16 + l16) * 32 + quad * 8];
            bfr[t] = *(const bf16x8*)&Bs[(wn + t * 16 + l16) * 32 + quad * 8];
        }
#pragma unroll
        for (int mt = 0; mt < 4; mt++)
#pragma unroll
            for (int nt = 0; nt < 4; nt++)
                acc[mt][nt] = __builtin_amdgcn_mfma_f32_16x16x32_bf16(
                    af[mt], bfr[nt], acc[mt][nt], 0, 0, 0);
    }

    const int mat = nI >> 3;
    const int nc0 = (nI & 7) * 128;
    const float* bias = (mat == 0) ? bq : (mat == 1) ? bk : bv;

    if (mat < 2) {
        ushort* Y = (mat == 0) ? q : k;
        // q pre-scaled by (1/sqrt(64)) * log2(e) so attn uses raw v_exp_f32
        const float scale = (mat == 0) ? 0.18033688f : 1.0f;
#pragma unroll
        for (int mt = 0; mt < 4; mt++) {
            int row = m0 + wm + mt * 16 + quad * 4;
#pragma unroll
            for (int nt = 0; nt < 4; nt++) {
                int col = nc0 + wn + nt * 16 + l16;
                float bvl = bias[col];
#pragma unroll
                for (int r = 0; r < 4; r++)
                    Y[(size_t)(row + r) * 1024 + col] = f2bf((acc[mt][nt][r] + bvl) * scale);
            }
        }
    } else {
        __syncthreads();
#pragma unroll
        for (int mt = 0; mt < 4; mt++) {
            int rowL = wm + mt * 16 + quad * 4;
#pragma unroll
            for (int nt = 0; nt < 4; nt++) {
                int colL = wn + nt * 16 + l16;
                float bvl = bias[nc0 + colL];
                ushort t4[4];
#pragma unroll
                for (int r = 0; r < 4; r++) t4[r] = f2bf(acc[mt][nt][r] + bvl);
                *(uint2*)&smem[colL * CS + rowL] = *(const uint2*)t4;
            }
        }
        __syncthreads();
        const int bb = m0 >> 11, tB = m0 & 2047;
#pragma unroll
        for (int it = 0; it < 8; it++) {
            int hdL = it * 16 + (tid >> 4);
            int tcL = (tid & 15) * 8;
            uint4 d = *(const uint4*)&smem[hdL * CS + tcL];
            int colG = nc0 + hdL;
            int hh = colG >> 6, hd = colG & 63;
            *(uint4*)&v[(size_t)((bb * 16 + hh) * 64 + hd) * 2048 + tB + tcL] = d;
        }
    }
}

// ---------------------------------------------------------------------------
// Out-proj GEMM (R11): ctx bf16 @ WTo -> out fp32. XCD-swizzled.
// ---------------------------------------------------------------------------
__global__ __launch_bounds__(256) void gemm_out(
    const ushort* __restrict__ Xb, const ushort* __restrict__ WT,
    const float* __restrict__ bias, float* __restrict__ Y)
{
    __shared__ ushort smem[12288];

    const int tid  = threadIdx.x;
    const int lane = tid & 63, wave = tid >> 6;
    const int l16  = lane & 15, quad = lane >> 4;
    const int wm   = (wave >> 1) * 64, wn = (wave & 1) * 32;
    const int flat = blockIdx.y * 16 + blockIdx.x;
    const int xcd  = flat & 7, lid = flat >> 3;
    const int m0   = (xcd * 4 + (lid & 3)) * 128;
    const int n0   = (lid >> 2) * 64;
    const int srow = lane >> 2, skoff = (lane & 3) * 8;

    f32x4 acc[4][2] = {};

#pragma unroll
    for (int c = 0; c < 2; c++) {
        int chunk = wave + c * 4;
        GLDS16(Xb + (size_t)(m0 + chunk * 16 + srow) * 1024 + skoff,
               smem + chunk * 512);
    }
    GLDS16(WT + (size_t)(n0 + wave * 16 + srow) * 1024 + skoff,
           smem + 8192 + wave * 512);

    for (int i = 0; i < 32; i++) {
        const int p = i & 1;
        __syncthreads();
        if (i < 31) {
            int k0 = (i + 1) * 32;
#pragma unroll
            for (int c = 0; c < 2; c++) {
                int chunk = wave + c * 4;
                GLDS16(Xb + (size_t)(m0 + chunk * 16 + srow) * 1024 + k0 + skoff,
                       smem + (p ^ 1) * 4096 + chunk * 512);
            }
            GLDS16(WT + (size_t)(n0 + wave * 16 + srow) * 1024 + k0 + skoff,
                   smem + 8192 + (p ^ 1) * 2048 + wave * 512);
        }
        const ushort* As = smem + p * 4096;
        const ushort* Bs = smem + 8192 + p * 2048;
        bf16x8 af[4], bfr[2];
#pragma unroll
        for (int t = 0; t < 4; t++)
            af[t] = *(const bf16x8*)&As[(wm + t * 16 + l16) * 32 + quad * 8];
#pragma unroll
        for (int t = 0; t < 2; t++)
            bfr[t] = *(const bf16x8*)&Bs[(wn + t * 16 + l16) * 32 + quad * 8];
#pragma unroll
        for (int mt = 0; mt < 4; mt++)
#pragma unroll
            for (int nt = 0; nt < 2; nt++)
                acc[mt][nt] = __builtin_amdgcn_mfma_f32_16x16x32_bf16(
                    af[mt], bfr[nt], acc[mt][nt], 0, 0, 0);
    }

#pragma unroll
    for (int mt = 0; mt < 4; mt++) {
        int row = m0 + wm + mt * 16 + quad * 4;
#pragma unroll
        for (int nt = 0; nt < 2; nt++) {
            int col = n0 + wn + nt * 16 + l16;
            float bvl = bias[col];
#pragma unroll
            for (int r = 0; r < 4; r++)
                Y[(size_t)(row + r) * 1024 + col] = acc[mt][nt][r] + bvl;
        }
    }
}

// ---------------------------------------------------------------------------
// Flash attention, R18: 512 blocks x 256 thr, 4 waves x 32 q-rows, 32x32x16
// MFMA. Swapped QK^T (S^T = K Q^T, q = lane&31) -> per-lane P rows; PV A-frag
// built in registers via v_perm pack + v_permlane32_swap (no Ps LDS panel).
// Double-buffered K/V (layouts identical to R9), 1 barrier/iter, XCD swizzle.
// ---------------------------------------------------------------------------
#define KVS 36

__global__ __launch_bounds__(256, 2) void attn(
    const ushort* __restrict__ Q, const ushort* __restrict__ Kb,
    const ushort* __restrict__ VT, ushort* __restrict__ CTX)
{
    const int id   = blockIdx.x;
    const int g    = (id & 7) * 4 + ((id >> 3) & 3);   // (b,h) group, XCD-local
    const int qc   = id >> 5;                           // q-chunk 0..15
    const int b    = g >> 4, h = g & 15;
    const int q0   = qc * 128;
    const int tid  = threadIdx.x;
    const int lane = tid & 63, wave = tid >> 6;
    const int l31  = lane & 31, hi = lane >> 5;
    const int wq   = wave * 32;
    const size_t base  = (size_t)b * 2048 * 1024 + (size_t)h * 64;
    const size_t vbase = (size_t)g * 64 * 2048;

    __shared__ ushort Ks[2][2][64 * KVS];   // [buf][d-half][key][..]
    __shared__ ushort Vs[2][2][64 * KVS];   // [buf][key-half][hd][..]

    // Q B-frags (pre-scaled by 0.125*log2e): lane holds Q[q=l31][dc*16+hi*8+e]
    bf16x8 aq[4];
    {
        const ushort* qp = Q + base + (size_t)(q0 + wq + l31) * 1024 + hi * 8;
#pragma unroll
        for (int dc = 0; dc < 4; dc++)
            aq[dc] = *(const bf16x8*)(qp + dc * 16);
    }

    f32x16 o[2] = {};        // O[q][hd]: col=hd(ht*32+l31), row q=(r&3)+8*(r>>2)+4*hi
    float  ls[4] = {};       // per-lane partial softmax denominators (q = l31)

    const int srow = tid >> 2;          // 0..63
    const int soff = (tid & 3) * 8;     // 0,8,16,24

    // prologue: stage tile 0 into buffer 0
    {
        const ushort* kp = Kb + base + (size_t)srow * 1024 + soff;
        uint4 ka = *(const uint4*)kp, ka2 = *(const uint4*)(kp + 32);
        const ushort* vp = VT + vbase + (size_t)srow * 2048 + soff;
        uint4 va = *(const uint4*)vp, va2 = *(const uint4*)(vp + 32);
        *(uint4*)&Ks[0][0][srow * KVS + soff] = ka;
        *(uint4*)&Ks[0][1][srow * KVS + soff] = ka2;
        *(uint4*)&Vs[0][0][srow * KVS + soff] = va;
        *(uint4*)&Vs[0][1][srow * KVS + soff] = va2;
    }

    for (int i = 0; i < 32; i++) {
        const int p = i & 1;
        __syncthreads();   // buf p staged + old readers of buf p^1 done

        // issue next-tile loads immediately (consumed at iter end)
        uint4 ka, ka2, va, va2;
        if (i < 31) {
            int j0 = (i + 1) * 64;
            const ushort* kp = Kb + base + (size_t)(j0 + srow) * 1024 + soff;
            ka = *(const uint4*)kp; ka2 = *(const uint4*)(kp + 32);
            const ushort* vp = VT + vbase + (size_t)srow * 2048 + j0 + soff;
            va = *(const uint4*)vp; va2 = *(const uint4*)(vp + 32);
        }

        // S^T = K Q^T  (M=key 64 -> 2 tiles, N=q 32).  A=K-frag, B=Q-frag.
        f32x16 sacc[2] = {};
#pragma unroll
        for (int dc = 0; dc < 4; dc++) {
            const int hf = dc >> 1, co = (dc & 1) * 16 + hi * 8;
            bf16x8 k0 = *(const bf16x8*)&Ks[p][hf][l31 * KVS + co];
            bf16x8 k1 = *(const bf16x8*)&Ks[p][hf][(32 + l31) * KVS + co];
            sacc[0] = __builtin_amdgcn_mfma_f32_32x32x16_bf16(k0, aq[dc], sacc[0], 0, 0, 0);
            sacc[1] = __builtin_amdgcn_mfma_f32_32x32x16_bf16(k1, aq[dc], sacc[1], 0, 0, 0);
        }

        // V B-frags (independent of sacc -> overlaps the exp/pack VALU work)
        bf16x8 bv[2][4];
#pragma unroll
        for (int c = 0; c < 4; c++) {
            const int hf = c >> 1, co = (c & 1) * 16 + hi * 8;
            bv[0][c] = *(const bf16x8*)&Vs[p][hf][l31 * KVS + co];
            bv[1][c] = *(const bf16x8*)&Vs[p][hf][(32 + l31) * KVS + co];
        }

        // p = 2^s (log2e pre-folded into q), pack pairs to bf16, then
        // cross-half exchange builds PV A-frags entirely in registers.
        // sacc[kt] reg r <-> key = kt*32 + (r&3) + 8*(r>>2) + 4*hi, q = l31.
        // pk[j] holds keys (2j',2j'+1) with j' = per-half ascending order:
        //   hi=0: {0,1},{2,3},{8,9},{10,11},{16,17},{18,19},{24,25},{26,27}
        //   hi=1: same +4.
        // Frag word w of chunk cl needs [lo-half keys | hi-half keys]:
        //   w0 = swap(pk[4cl+0], pk[4cl+2]).a  (a'=[a(0:31)|b(0:31)])
        //   w2 = swap(pk[4cl+0], pk[4cl+2]).b  (b'=[a(32:63)|b(32:63)])
        bf16x8 pf[4];
#pragma unroll
        for (int kt = 0; kt < 2; kt++) {
            unsigned int pk[8];
#pragma unroll
            for (int j = 0; j < 8; j++) {
                float e0 = __builtin_amdgcn_exp2f(sacc[kt][2 * j]);
                float e1 = __builtin_amdgcn_exp2f(sacc[kt][2 * j + 1]);
                ls[j & 3] += e0 + e1;
                // low16 = bf16(e0) (even key), high16 = bf16(e1) (odd key)
                pk[j] = __builtin_amdgcn_perm(__float_as_uint(e1),
                                              __float_as_uint(e0), 0x07060302u);
            }
#pragma unroll
            for (int cl = 0; cl < 2; cl++) {
                unsigned int w0 = pk[4 * cl + 0], w2 = pk[4 * cl + 2];
                unsigned int w1 = pk[4 * cl + 1], w3 = pk[4 * cl + 3];
                pl32swap(w0, w2);   // w0 -> frag word0, w2 -> frag word2
                pl32swap(w1, w3);   // w1 -> frag word1, w3 -> frag word3
                u32x4 wv = {w0, w1, w2, w3};
                pf[kt * 2 + cl] = __builtin_bit_cast(bf16x8, wv);
            }
        }

        // O += P V   (A = P-frag from regs, B = V from LDS)
#pragma unroll
        for (int c = 0; c < 4; c++) {
            o[0] = __builtin_amdgcn_mfma_f32_32x32x16_bf16(pf[c], bv[0][c], o[0], 0, 0, 0);
            o[1] = __builtin_amdgcn_mfma_f32_32x32x16_bf16(pf[c], bv[1][c], o[1], 0, 0, 0);
        }

        // stage next tile into buf p^1
        if (i < 31) {
            *(uint4*)&Ks[p ^ 1][0][srow * KVS + soff] = ka;
            *(uint4*)&Ks[p ^ 1][1][srow * KVS + soff] = ka2;
            *(uint4*)&Vs[p ^ 1][0][srow * KVS + soff] = va;
            *(uint4*)&Vs[p ^ 1][1][srow * KVS + soff] = va2;
        }
    }

    // softmax denominator: per-lane partials hold q = l31; merge lane halves
    float lsum = (ls[0] + ls[1]) + (ls[2] + ls[3]);
    lsum += __shfl_xor(lsum, 32, 64);
    float inv = 1.f / lsum;

    // normalize + write: o[ht] reg r -> q-row (r&3)+8*(r>>2)+4*hi, hd ht*32+l31
#pragma unroll
    for (int r = 0; r < 16; r++) {
        const int qrow = (r & 3) + 8 * (r >> 2) + 4 * hi;
        const float invr = __shfl(inv, qrow, 64);
        const size_t rowb = base + (size_t)(q0 + wq + qrow) * 1024;
#pragma unroll
        for (int ht = 0; ht < 2; ht++)
            CTX[rowb + ht * 32 + l31] = f2bf(o[ht][r] * invr);
    }
}

// ---------------------------------------------------------------------------
extern "C" void kernel_launch(void* const* d_in, const int* in_sizes, int n_in,
                              void* d_out, int out_size, void* d_ws, size_t ws_size,
                              hipStream_t stream)
{
    (void)in_sizes; (void)n_in; (void)out_size; (void)ws_size;
    const float* x  = (const float*)d_in[0];
    const float* Wq = (const float*)d_in[1];
    const float* bq = (const float*)d_in[2];
    const float* Wk = (const float*)d_in[3];
    const float* bk = (const float*)d_in[4];
    const float* Wv = (const float*)d_in[5];
    const float* bv = (const float*)d_in[6];
    const float* Wo = (const float*)d_in[7];
    const float* bo = (const float*)d_in[8];

    char* ws = (char*)d_ws;
    const size_t MT = (size_t)4096 * 1024 * 2;   // 8 MB per [4096][1024] bf16
    ushort* q  = (ushort*)(ws + 0 * MT);         // q, later ctx (alias-safe)
    ushort* k  = (ushort*)(ws + 1 * MT);
    ushort* v  = (ushort*)(ws + 2 * MT);         // vT[(b*16+h)*64+hd][t]
    ushort* WT = (ushort*)(ws + 3 * MT);         // 4 x 1M bf16 (q,k,v,o stacked)
    ushort* xb = (ushort*)d_out;                 // scratch in out (dead before gemm_out)

    conv<<<dim3(4096), 256, 0, stream>>>(x, Wq, Wk, Wv, Wo, xb, WT);

    gemm_qkv<<<dim3(24, 32), 256, 0, stream>>>(xb, WT, bq, bk, bv, q, k, v);

    attn<<<dim3(512), 256, 0, stream>>>(q, k, v, q /*ctx aliases q*/);

    gemm_out<<<dim3(16, 32), 256, 0, stream>>>(q, WT + 3 * 1048576, bo, (float*)d_out);
}